// Round 10
// baseline (375.978 us; speedup 1.0000x reference)
//
#include <hip/hip_runtime.h>
#include <math.h>

// Problem constants
// B=2, dim=128, H=256, W=256 -> half res 128x128, heads=8, c=16, K=7, G=16, gc=8
#define BB 2
#define DIM 128
#define HH 256
#define WW 256
#define HWFULL 65536   // 256*256
#define HHW 16384      // 128*128
#define HEADS 8
#define CHEAD 16
#define KK 7
#define GG 16
#define GC 8
#define NCHUNK 8

// ---------------------------------------------------------------------------
// K1+K2 fused, single-pass: x_dwt = HaarDWT(relu(reduce_w @ x + reduce_b))
// Thread = (half-res pixel, quad position). 32 acc regs; per c: 1 coalesced
// load + 32 FMA (weights via wave-uniform scalar loads). Haar combine via
// 2 shfl_xor butterflies across the 4-lane position group. x read ONCE.
// grid: (16384/64, B), block 256 (=64 px * 4 pos)
__global__ __launch_bounds__(256) void k_reduce_dwt(
        const float* __restrict__ x, const float* __restrict__ w,
        const float* __restrict__ bias, float* __restrict__ xd) {
    int t = threadIdx.x;
    int pix = t >> 2, pos = t & 3;
    int p = blockIdx.x * 64 + pix;      // half-res pixel
    int b = blockIdx.y;
    int hq = p >> 7, wq = p & 127;
    int gy = 2 * hq + (pos >> 1), gx = 2 * wq + (pos & 1);

    float acc[32];
#pragma unroll
    for (int oc = 0; oc < 32; oc++) acc[oc] = bias[oc];

    const float* xb = x + (size_t)b * 128 * HWFULL + gy * 256 + gx;
#pragma unroll 4
    for (int c = 0; c < 128; c++) {
        float xv = xb[(size_t)c * HWFULL];
#pragma unroll
        for (int oc = 0; oc < 32; oc++)
            acc[oc] = fmaf(xv, w[oc * 128 + c], acc[oc]);   // w uniform -> s_load
    }

    // Haar butterfly across positions (lanes xor 1, xor 2)
    float s1 = (pos & 1) ? -1.f : 1.f;
    float s2 = (pos & 2) ? -1.f : 1.f;
    int s = ((pos & 1) << 1) | (pos >> 1);   // pos0->ll(0), pos1->hl(2), pos2->lh(1), pos3->hh(3)
    float* xo = xd + (size_t)b * 128 * HHW + (size_t)s * 32 * HHW + p;
#pragma unroll
    for (int oc = 0; oc < 32; oc++) {
        float v = fmaxf(acc[oc], 0.f);
        float t1 = __shfl_xor(v, 1);
        float r1 = fmaf(s1, v, t1);          // pos even: v+t1 ; odd: t1-v
        float t2 = __shfl_xor(r1, 2);
        float r2 = fmaf(s2, r1, t2);
        xo[(size_t)oc * HHW] = 0.5f * r2;
    }
}

// ---------------------------------------------------------------------------
// qkv conv1x1: 4 consecutive pixels per thread via float4; weights read with
// wave-uniform indices directly from global -> scalar loads (no LDS).
// grid: (P/1024, OC/OCB, B)
template<int OCB, int IC>
__global__ __launch_bounds__(256) void k_conv1x1_f4(
        const float* __restrict__ x, const float* __restrict__ w,
        float* __restrict__ y, int OC, int P) {
    int p0  = (blockIdx.x * 256 + threadIdx.x) * 4;
    int oc0 = blockIdx.y * OCB;
    int b   = blockIdx.z;

    float acc[4][OCB];
#pragma unroll
    for (int px = 0; px < 4; px++)
#pragma unroll
        for (int oc = 0; oc < OCB; oc++) acc[px][oc] = 0.f;

    const float* xb = x + (size_t)b * IC * P;
    const float* wb = w + (size_t)oc0 * IC;
#pragma unroll 4
    for (int c = 0; c < IC; c++) {
        float4 xv = *reinterpret_cast<const float4*>(&xb[(size_t)c * P + p0]);
#pragma unroll
        for (int oc = 0; oc < OCB; oc++) {
            float wv = wb[oc * IC + c];      // uniform -> s_load, K$-contiguous in c
            acc[0][oc] = fmaf(xv.x, wv, acc[0][oc]);
            acc[1][oc] = fmaf(xv.y, wv, acc[1][oc]);
            acc[2][oc] = fmaf(xv.z, wv, acc[2][oc]);
            acc[3][oc] = fmaf(xv.w, wv, acc[3][oc]);
        }
    }
    float* yb = y + ((size_t)b * OC + oc0) * P;
#pragma unroll
    for (int oc = 0; oc < OCB; oc++) {
        float4 o = make_float4(acc[0][oc], acc[1][oc], acc[2][oc], acc[3][oc]);
        *reinterpret_cast<float4*>(&yb[(size_t)oc * P + p0]) = o;
    }
}

// ---------------------------------------------------------------------------
// Generic conv1x1 (small OC): scalar weights, no LDS.
template<int PX, int OCB, int IC>
__global__ __launch_bounds__(256) void k_conv1x1(
        const float* __restrict__ x, const float* __restrict__ w,
        const float* __restrict__ bias, float* __restrict__ y,
        int OC, int P, int do_relu) {
    int p0  = blockIdx.x * (256 * PX) + threadIdx.x;
    int oc0 = blockIdx.y * OCB;
    int b   = blockIdx.z;

    float acc[PX][OCB];
#pragma unroll
    for (int px = 0; px < PX; px++)
#pragma unroll
        for (int oc = 0; oc < OCB; oc++) acc[px][oc] = bias ? bias[oc0 + oc] : 0.f;

    const float* xb = x + (size_t)b * IC * P;
    const float* wb = w + (size_t)oc0 * IC;
#pragma unroll 4
    for (int c = 0; c < IC; c++) {
        float xv[PX];
#pragma unroll
        for (int px = 0; px < PX; px++) xv[px] = xb[(size_t)c * P + p0 + px * 256];
#pragma unroll
        for (int oc = 0; oc < OCB; oc++) {
            float wv = wb[oc * IC + c];      // uniform -> s_load
#pragma unroll
            for (int px = 0; px < PX; px++)
                acc[px][oc] = fmaf(xv[px], wv, acc[px][oc]);
        }
    }
    float* yb = y + ((size_t)b * OC + oc0) * P;
#pragma unroll
    for (int oc = 0; oc < OCB; oc++)
#pragma unroll
        for (int px = 0; px < PX; px++) {
            float v = acc[px][oc];
            yb[(size_t)oc * P + p0 + px * 256] = do_relu ? fmaxf(v, 0.f) : v;
        }
}

// ---------------------------------------------------------------------------
// K4: depthwise 3x3, pad 1, LDS-tiled. qkv0:(B,384,128,128) -> qkv1 (same)
#define DWR 32
__global__ __launch_bounds__(256) void k_dw3x3(const float* __restrict__ x,
                                               const float* __restrict__ w,
                                               float* __restrict__ y) {
    int blk = blockIdx.x;
    int rt = blk & 3;              // row-tile
    int ch = blk >> 2;             // 0..B*384-1
    int r0 = rt * DWR;

    __shared__ float tile[(DWR + 2) * 130];
    const float* xp = x + (size_t)ch * HHW;

    for (int i = threadIdx.x; i < (DWR + 2) * 130; i += 256) {
        int r = i / 130, c = i % 130;
        int gy = r0 + r - 1, gx = c - 1;
        float v = 0.f;
        if (gy >= 0 && gy < 128 && gx >= 0 && gx < 128)
            v = xp[gy * 128 + gx];
        tile[i] = v;
    }
    __syncthreads();

    const float* wc = w + (size_t)(ch % 384) * 9;
    float w00 = wc[0], w01 = wc[1], w02 = wc[2];
    float w10 = wc[3], w11 = wc[4], w12 = wc[5];
    float w20 = wc[6], w21 = wc[7], w22 = wc[8];

    int tx = threadIdx.x & 127;          // output col
    int ty = threadIdx.x >> 7;           // 0/1: row half
    int lrbase = ty * 16;                // first lds row (top of window)

    const float* lp = &tile[lrbase * 130 + tx];
    float t0 = lp[0], t1 = lp[1], t2 = lp[2];
    lp += 130;
    float m0 = lp[0], m1 = lp[1], m2 = lp[2];

    float* yp = y + (size_t)ch * HHW + (r0 + ty * 16) * 128 + tx;
#pragma unroll
    for (int i = 0; i < 16; i++) {
        lp += 130;
        float b0 = lp[0], b1 = lp[1], b2 = lp[2];
        float a0 = t0 * w00 + t1 * w01 + t2 * w02;
        float a1 = m0 * w10 + m1 * w11 + m2 * w12;
        float a2 = b0 * w20 + b1 * w21 + b2 * w22;
        yp[i * 128] = a0 + a1 + a2;
        t0 = m0; t1 = m1; t2 = m2;
        m0 = b0; m1 = b1; m2 = b2;
    }
}

// ---------------------------------------------------------------------------
// K5a: L2 norms over spatial dim for q (ch 0..127) and k (ch 128..255)
__global__ void k_norms(const float* __restrict__ qkv, float* __restrict__ norms) {
    int blk = blockIdx.x;          // B*256
    int b = blk >> 8;
    int ch = blk & 255;
    const float* p = qkv + ((size_t)b * 384 + ch) * HHW;
    float s = 0.f;
    for (int i = threadIdx.x; i < HHW; i += 256) {
        float v = p[i];
        s = fmaf(v, v, s);
    }
#pragma unroll
    for (int off = 32; off > 0; off >>= 1) s += __shfl_down(s, off);
    __shared__ float red[4];
    int lane = threadIdx.x & 63, wid = threadIdx.x >> 6;
    if (lane == 0) red[wid] = s;
    __syncthreads();
    if (threadIdx.x == 0) {
        float t = red[0] + red[1] + red[2] + red[3];
        norms[b * 256 + ch] = fmaxf(sqrtf(t), 1e-12f);
    }
}

// ---------------------------------------------------------------------------
// K5b: partial S over N-chunks. grid (B*8*16, NCHUNK).
__global__ void k_attn_s(const float* __restrict__ qkv, float* __restrict__ Spart) {
    int blk = blockIdx.x;
    int chunk = blockIdx.y;
    int ci = blk & 15;
    int hd = (blk >> 4) & 7;
    int b  = blk >> 7;
    const float* q = qkv + ((size_t)b * 384 + hd * CHEAD + ci) * HHW;
    const float* k = qkv + ((size_t)b * 384 + 128 + hd * CHEAD) * HHW;

    float acc[16];
#pragma unroll
    for (int cj = 0; cj < 16; cj++) acc[cj] = 0.f;

    int n0 = chunk * (HHW / NCHUNK);
    int n1 = n0 + (HHW / NCHUNK);
    for (int n = n0 + threadIdx.x; n < n1; n += 256) {
        float qv = q[n];
#pragma unroll
        for (int cj = 0; cj < 16; cj++) acc[cj] = fmaf(qv, k[(size_t)cj * HHW + n], acc[cj]);
    }

    __shared__ float red[4][16];
    int lane = threadIdx.x & 63, wid = threadIdx.x >> 6;
#pragma unroll
    for (int cj = 0; cj < 16; cj++) {
        float v = acc[cj];
#pragma unroll
        for (int off = 32; off > 0; off >>= 1) v += __shfl_down(v, off);
        if (lane == 0) red[wid][cj] = v;
    }
    __syncthreads();
    if (threadIdx.x < 16) {
        int cj = threadIdx.x;
        float s = red[0][cj] + red[1][cj] + red[2][cj] + red[3][cj];
        Spart[(size_t)chunk * 4096 + ((((size_t)b * 8 + hd) * 16 + ci) * 16 + cj)] = s;
    }
}

// K5c: attn = relu( (sum_chunks Spart)/(qn*kn) * temp[h] )
__global__ void k_attn_norm(const float* __restrict__ Spart, const float* __restrict__ norms,
                            const float* __restrict__ temp, float* __restrict__ attn) {
    int i = blockIdx.x * 256 + threadIdx.x;  // 4096
    if (i >= BB * 8 * 16 * 16) return;
    int cj = i & 15, ci = (i >> 4) & 15, hd = (i >> 8) & 7, b = i >> 11;
    float s = 0.f;
#pragma unroll
    for (int ch = 0; ch < NCHUNK; ch++) s += Spart[(size_t)ch * 4096 + i];
    float qn = norms[b * 256 + hd * CHEAD + ci];
    float kn = norms[b * 256 + 128 + hd * CHEAD + cj];
    attn[i] = fmaxf(s / (qn * kn) * temp[hd], 0.f);
}

// ---------------------------------------------------------------------------
// K6: one head per block: out[b,hd*16+ci,n] = sum_cj attn[ci,cj]*v[cj,n]
__global__ void k_attn_apply(const float* __restrict__ qkv, const float* __restrict__ attn,
                             float* __restrict__ out) {
    int n = blockIdx.x * 256 + threadIdx.x;
    int hd = blockIdx.y;
    int b = blockIdx.z;

    __shared__ float at[256];
    at[threadIdx.x] = attn[((size_t)b * 8 + hd) * 256 + threadIdx.x];
    __syncthreads();

    const float* v = qkv + ((size_t)b * 384 + 256 + hd * CHEAD) * HHW + n;
    float vv[16];
#pragma unroll
    for (int cj = 0; cj < 16; cj++) vv[cj] = v[(size_t)cj * HHW];

    float* ob = out + ((size_t)b * 128 + hd * CHEAD) * HHW + n;
#pragma unroll
    for (int ci = 0; ci < 16; ci++) {
        float acc = 0.f;
        const float* ar = &at[ci * 16];
#pragma unroll
        for (int cj = 0; cj < 16; cj++) acc = fmaf(ar[cj], vv[cj], acc);
        ob[(size_t)ci * HHW] = acc;
    }
}

// ---------------------------------------------------------------------------
// K8: fused wgen + dynamic 7x7 grouped conv — tap-outer, spill-free.
__global__ void k_dyn(const float* __restrict__ oa, const float* __restrict__ t,
                      const float* __restrict__ w2, const float* __restrict__ b2,
                      float* __restrict__ od) {
    int tile = blockIdx.x;
    int g = blockIdx.y;
    int b = blockIdx.z;
    int ty0 = (tile >> 3) * 16, tx0 = (tile & 7) * 16;
    int ty = threadIdx.x >> 4, tx = threadIdx.x & 15;
    int y = ty0 + ty, x = tx0 + tx;

    // stage out_attn patch: 8 ch x 22 x 22
    __shared__ __align__(16) float patch[8][22][22];
    const float* oab = oa + ((size_t)b * 128 + g * GC) * HHW;
    for (int i = threadIdx.x; i < 8 * 22 * 22; i += 256) {
        int cc = i / 484;
        int rem = i % 484;
        int py = rem / 22, px = rem % 22;
        int sy = ty0 + py - 3, sx = tx0 + px - 3;
        float v = 0.f;
        if (sy >= 0 && sy < 128 && sx >= 0 && sx < 128)
            v = oab[(size_t)cc * HHW + sy * 128 + sx];
        patch[cc][py][px] = v;
    }
    __syncthreads();

    // t[32] for this pixel -> registers (coalesced loads)
    const float* tb = t + (size_t)b * 32 * HHW + y * 128 + x;
    float tv[32];
#pragma unroll
    for (int m = 0; m < 32; m++) tv[m] = tb[(size_t)m * HHW];

    const float* w2g = w2 + (size_t)g * 49 * 32;
    const float* b2g = b2 + (size_t)g * 49;

    float acc[8];
#pragma unroll
    for (int cc = 0; cc < 8; cc++) acc[cc] = 0.f;

    for (int kk = 0; kk < 49; kk++) {
        float w0 = b2g[kk], w1 = 0.f;
        const float* wr = &w2g[kk * 32];
#pragma unroll
        for (int m = 0; m < 32; m += 2) {
            w0 = fmaf(wr[m],     tv[m],     w0);
            w1 = fmaf(wr[m + 1], tv[m + 1], w1);
        }
        float wv = w0 + w1;
        int di = kk / 7, dj = kk % 7;
#pragma unroll
        for (int cc = 0; cc < 8; cc++)
            acc[cc] = fmaf(patch[cc][ty + di][tx + dj], wv, acc[cc]);
    }

    float* odb = od + ((size_t)b * 128 + g * GC) * HHW + y * 128 + x;
#pragma unroll
    for (int cc = 0; cc < 8; cc++) odb[(size_t)cc * HHW] = acc[cc];
}

// ---------------------------------------------------------------------------
// K9: fused inverse DWT + projection
__global__ void k_idwt_proj(const float* __restrict__ dyn, const float* __restrict__ pw,
                            float* __restrict__ out) {
    int p = blockIdx.x * 256 + threadIdx.x;   // half-res pixel
    int oc0 = blockIdx.y * 16;
    int b = blockIdx.z;
    int y = p >> 7, x = p & 127;

    __shared__ __align__(16) float wl[32 * 16];   // wl[c*16+oc]
    for (int i = threadIdx.x; i < 512; i += 256) {
        int oc = i & 15, c = i >> 4;
        wl[i] = pw[(size_t)(oc0 + oc) * 32 + c];
    }
    __syncthreads();

    float u0[16], u1[16], u2[16], u3[16];
#pragma unroll
    for (int oc = 0; oc < 16; oc++) { u0[oc]=0.f; u1[oc]=0.f; u2[oc]=0.f; u3[oc]=0.f; }

    const float* db = dyn + (size_t)b * 128 * HHW + p;
    for (int c = 0; c < 32; c++) {
        float d0 = db[(size_t)(0 * 32 + c) * HHW];
        float d1 = db[(size_t)(1 * 32 + c) * HHW];
        float d2 = db[(size_t)(2 * 32 + c) * HHW];
        float d3 = db[(size_t)(3 * 32 + c) * HHW];
        const float* wc = &wl[c * 16];
#pragma unroll
        for (int oc = 0; oc < 16; oc++) {
            float wv = wc[oc];
            u0[oc] = fmaf(wv, d0, u0[oc]);
            u1[oc] = fmaf(wv, d1, u1[oc]);
            u2[oc] = fmaf(wv, d2, u2[oc]);
            u3[oc] = fmaf(wv, d3, u3[oc]);
        }
    }

    float* ob = out + ((size_t)b * 128 + oc0) * HWFULL + (2 * y) * 256 + 2 * x;
#pragma unroll
    for (int oc = 0; oc < 16; oc++) {
        float a = u0[oc], bq = u1[oc], c2 = u2[oc], dd = u3[oc];
        float2 top, bot;
        top.x = 0.5f * (a + bq + c2 + dd);
        top.y = 0.5f * (a + bq - c2 - dd);
        bot.x = 0.5f * (a - bq + c2 - dd);
        bot.y = 0.5f * (a - bq - c2 + dd);
        float* o = ob + (size_t)oc * HWFULL;
        *reinterpret_cast<float2*>(&o[0])   = top;
        *reinterpret_cast<float2*>(&o[256]) = bot;
    }
}

// ---------------------------------------------------------------------------
extern "C" void kernel_launch(void* const* d_in, const int* in_sizes, int n_in,
                              void* d_out, int out_size, void* d_ws, size_t ws_size,
                              hipStream_t stream) {
    const float* x        = (const float*)d_in[0];
    const float* reduce_w = (const float*)d_in[1];
    const float* reduce_b = (const float*)d_in[2];
    const float* qkv_w    = (const float*)d_in[3];
    const float* qkv_dw   = (const float*)d_in[4];
    const float* temp     = (const float*)d_in[5];
    const float* fil_w1   = (const float*)d_in[6];
    const float* fil_b1   = (const float*)d_in[7];
    const float* fil_w2   = (const float*)d_in[8];
    const float* fil_b2   = (const float*)d_in[9];
    const float* proj_w   = (const float*)d_in[10];
    float* out = (float*)d_out;

    // workspace layout (floats)
    float* ws = (float*)d_ws;
    float* x_dwt = ws;                                   // B*128*16384
    float* big   = x_dwt + (size_t)BB * 128 * HHW;       // B*384*16384: qkv0 -> out_attn
    float* qkv1  = big   + (size_t)BB * 384 * HHW;       // B*384*16384
    float* tbuf  = qkv1  + (size_t)BB * 384 * HHW;       // B*32*16384
    float* norms = tbuf  + (size_t)BB * 32 * HHW;        // 512
    float* Spart = norms + 512;                          // NCHUNK*4096
    float* attn  = Spart + NCHUNK * 4096;                // 4096
    float* qkv0 = big;
    float* out_attn = big;     // alias (qkv0 dead after dw3x3)
    float* out_dyn = x_dwt;    // alias (x_dwt dead after t computed)

    // 1+2. fused reduce conv + relu + Haar DWT (single pass over x)
    k_reduce_dwt<<<dim3(HHW / 64, BB), 256, 0, stream>>>(x, reduce_w, reduce_b, x_dwt);
    // 3. qkv pointwise (float4 pixels, scalar weights)
    k_conv1x1_f4<16, 128><<<dim3(HHW / 1024, 384 / 16, BB), 256, 0, stream>>>(
        x_dwt, qkv_w, qkv0, 384, HHW);
    // 4. depthwise 3x3 (LDS-tiled)
    k_dw3x3<<<dim3(BB * 384 * 4), 256, 0, stream>>>(qkv0, qkv_dw, qkv1);
    // 5. attention
    k_norms<<<dim3(BB * 256), 256, 0, stream>>>(qkv1, norms);
    k_attn_s<<<dim3(BB * 8 * 16, NCHUNK), 256, 0, stream>>>(qkv1, Spart);
    k_attn_norm<<<dim3(16), 256, 0, stream>>>(Spart, norms, temp, attn);
    k_attn_apply<<<dim3(HHW / 256, HEADS, BB), 256, 0, stream>>>(qkv1, attn, out_attn);
    // 6. filter branch: t = relu(W1 @ x_dwt + b1)  (scalar weights)
    k_conv1x1<1, 8, 128><<<dim3(HHW / 256, 4, BB), 256, 0, stream>>>(
        x_dwt, fil_w1, fil_b1, tbuf, 32, HHW, 1);
    // 7. fused wgen + dynamic conv (tap-outer)
    k_dyn<<<dim3(64, GG, BB), 256, 0, stream>>>(out_attn, tbuf, fil_w2, fil_b2, out_dyn);
    // 8. fused idwt + projection
    k_idwt_proj<<<dim3(HHW / 256, 8, BB), 256, 0, stream>>>(out_dyn, proj_w, out);
}

// Round 12
// 336.154 us; speedup vs baseline: 1.1185x; 1.1185x over previous
//
#include <hip/hip_runtime.h>
#include <math.h>

// Problem constants
// B=2, dim=128, H=256, W=256 -> half res 128x128, heads=8, c=16, K=7, G=16, gc=8
#define BB 2
#define DIM 128
#define HH 256
#define WW 256
#define HWFULL 65536   // 256*256
#define HHW 16384      // 128*128
#define HEADS 8
#define CHEAD 16
#define KK 7
#define GG 16
#define GC 8
#define NCHUNK 8

// ---------------------------------------------------------------------------
// K1+K2 fused (round-5 validated design): x_dwt = HaarDWT(relu(reduce_w@x+b))
// Thread = one half-res pixel x 8 out-channels; 2x2 full-res quad accumulated
// in registers (32 acc), relu+Haar in-register, written directly.
// grid: (16384/128, 4, B), block 128
__global__ __launch_bounds__(128) void k_reduce_dwt(
        const float* __restrict__ x, const float* __restrict__ w,
        const float* __restrict__ bias, float* __restrict__ xd) {
    int p   = blockIdx.x * 128 + threadIdx.x;   // half-res pixel
    int oc0 = blockIdx.y * 8;
    int b   = blockIdx.z;
    int hq = p >> 7, wq = p & 127;

    __shared__ __align__(16) float wl[128 * 8];   // wl[c*8+oc]
    for (int i = threadIdx.x; i < 128 * 8; i += 128) {
        int oc = i & 7, c = i >> 3;
        wl[i] = w[(size_t)(oc0 + oc) * 128 + c];
    }
    __syncthreads();

    float accA[8], accB[8], accC[8], accD[8];   // TL, TR, BL, BR
#pragma unroll
    for (int oc = 0; oc < 8; oc++) {
        float bv = bias[oc0 + oc];
        accA[oc] = bv; accB[oc] = bv; accC[oc] = bv; accD[oc] = bv;
    }

    const float* xb = x + (size_t)b * 128 * HWFULL;
    int rowT = (2 * hq) * 256 + 2 * wq;
    int rowB = rowT + 256;
#pragma unroll 4
    for (int c = 0; c < 128; c++) {
        float2 top = *reinterpret_cast<const float2*>(&xb[(size_t)c * HWFULL + rowT]);
        float2 bot = *reinterpret_cast<const float2*>(&xb[(size_t)c * HWFULL + rowB]);
        const float4* wc = reinterpret_cast<const float4*>(&wl[c * 8]);
        float4 w40 = wc[0], w41 = wc[1];
        float wv[8] = {w40.x, w40.y, w40.z, w40.w, w41.x, w41.y, w41.z, w41.w};
#pragma unroll
        for (int oc = 0; oc < 8; oc++) {
            accA[oc] = fmaf(top.x, wv[oc], accA[oc]);
            accB[oc] = fmaf(top.y, wv[oc], accB[oc]);
            accC[oc] = fmaf(bot.x, wv[oc], accC[oc]);
            accD[oc] = fmaf(bot.y, wv[oc], accD[oc]);
        }
    }

    float* xbase = xd + (size_t)b * 128 * HHW + p;
#pragma unroll
    for (int oc = 0; oc < 8; oc++) {
        float a = fmaxf(accA[oc], 0.f);
        float bq = fmaxf(accB[oc], 0.f);
        float c2 = fmaxf(accC[oc], 0.f);
        float d = fmaxf(accD[oc], 0.f);
        int ch = oc0 + oc;
        xbase[(size_t)(0 * 32 + ch) * HHW] = 0.5f * (a + bq + c2 + d);   // ll
        xbase[(size_t)(1 * 32 + ch) * HHW] = 0.5f * (a + bq - c2 - d);   // lh
        xbase[(size_t)(2 * 32 + ch) * HHW] = 0.5f * (a - bq + c2 - d);   // hl
        xbase[(size_t)(3 * 32 + ch) * HHW] = 0.5f * (a - bq - c2 + d);   // hh
    }
}

// ---------------------------------------------------------------------------
// qkv conv1x1: 4 consecutive pixels per thread via float4; weights read with
// wave-uniform indices directly from global -> scalar loads (no LDS).
// grid: (P/1024, OC/OCB, B)
template<int OCB, int IC>
__global__ __launch_bounds__(256) void k_conv1x1_f4(
        const float* __restrict__ x, const float* __restrict__ w,
        float* __restrict__ y, int OC, int P) {
    int p0  = (blockIdx.x * 256 + threadIdx.x) * 4;
    int oc0 = blockIdx.y * OCB;
    int b   = blockIdx.z;

    float acc[4][OCB];
#pragma unroll
    for (int px = 0; px < 4; px++)
#pragma unroll
        for (int oc = 0; oc < OCB; oc++) acc[px][oc] = 0.f;

    const float* xb = x + (size_t)b * IC * P;
    const float* wb = w + (size_t)oc0 * IC;
#pragma unroll 4
    for (int c = 0; c < IC; c++) {
        float4 xv = *reinterpret_cast<const float4*>(&xb[(size_t)c * P + p0]);
#pragma unroll
        for (int oc = 0; oc < OCB; oc++) {
            float wv = wb[oc * IC + c];      // uniform -> s_load, K$-contiguous in c
            acc[0][oc] = fmaf(xv.x, wv, acc[0][oc]);
            acc[1][oc] = fmaf(xv.y, wv, acc[1][oc]);
            acc[2][oc] = fmaf(xv.z, wv, acc[2][oc]);
            acc[3][oc] = fmaf(xv.w, wv, acc[3][oc]);
        }
    }
    float* yb = y + ((size_t)b * OC + oc0) * P;
#pragma unroll
    for (int oc = 0; oc < OCB; oc++) {
        float4 o = make_float4(acc[0][oc], acc[1][oc], acc[2][oc], acc[3][oc]);
        *reinterpret_cast<float4*>(&yb[(size_t)oc * P + p0]) = o;
    }
}

// ---------------------------------------------------------------------------
// Generic conv1x1 (small OC): scalar weights, no LDS.
template<int PX, int OCB, int IC>
__global__ __launch_bounds__(256) void k_conv1x1(
        const float* __restrict__ x, const float* __restrict__ w,
        const float* __restrict__ bias, float* __restrict__ y,
        int OC, int P, int do_relu) {
    int p0  = blockIdx.x * (256 * PX) + threadIdx.x;
    int oc0 = blockIdx.y * OCB;
    int b   = blockIdx.z;

    float acc[PX][OCB];
#pragma unroll
    for (int px = 0; px < PX; px++)
#pragma unroll
        for (int oc = 0; oc < OCB; oc++) acc[px][oc] = bias ? bias[oc0 + oc] : 0.f;

    const float* xb = x + (size_t)b * IC * P;
    const float* wb = w + (size_t)oc0 * IC;
#pragma unroll 4
    for (int c = 0; c < IC; c++) {
        float xv[PX];
#pragma unroll
        for (int px = 0; px < PX; px++) xv[px] = xb[(size_t)c * P + p0 + px * 256];
#pragma unroll
        for (int oc = 0; oc < OCB; oc++) {
            float wv = wb[oc * IC + c];      // uniform -> s_load
#pragma unroll
            for (int px = 0; px < PX; px++)
                acc[px][oc] = fmaf(xv[px], wv, acc[px][oc]);
        }
    }
    float* yb = y + ((size_t)b * OC + oc0) * P;
#pragma unroll
    for (int oc = 0; oc < OCB; oc++)
#pragma unroll
        for (int px = 0; px < PX; px++) {
            float v = acc[px][oc];
            yb[(size_t)oc * P + p0 + px * 256] = do_relu ? fmaxf(v, 0.f) : v;
        }
}

// ---------------------------------------------------------------------------
// K4: depthwise 3x3, pad 1, LDS-tiled. qkv0:(B,384,128,128) -> qkv1 (same)
#define DWR 32
__global__ __launch_bounds__(256) void k_dw3x3(const float* __restrict__ x,
                                               const float* __restrict__ w,
                                               float* __restrict__ y) {
    int blk = blockIdx.x;
    int rt = blk & 3;              // row-tile
    int ch = blk >> 2;             // 0..B*384-1
    int r0 = rt * DWR;

    __shared__ float tile[(DWR + 2) * 130];
    const float* xp = x + (size_t)ch * HHW;

    for (int i = threadIdx.x; i < (DWR + 2) * 130; i += 256) {
        int r = i / 130, c = i % 130;
        int gy = r0 + r - 1, gx = c - 1;
        float v = 0.f;
        if (gy >= 0 && gy < 128 && gx >= 0 && gx < 128)
            v = xp[gy * 128 + gx];
        tile[i] = v;
    }
    __syncthreads();

    const float* wc = w + (size_t)(ch % 384) * 9;
    float w00 = wc[0], w01 = wc[1], w02 = wc[2];
    float w10 = wc[3], w11 = wc[4], w12 = wc[5];
    float w20 = wc[6], w21 = wc[7], w22 = wc[8];

    int tx = threadIdx.x & 127;          // output col
    int ty = threadIdx.x >> 7;           // 0/1: row half
    int lrbase = ty * 16;                // first lds row (top of window)

    const float* lp = &tile[lrbase * 130 + tx];
    float t0 = lp[0], t1 = lp[1], t2 = lp[2];
    lp += 130;
    float m0 = lp[0], m1 = lp[1], m2 = lp[2];

    float* yp = y + (size_t)ch * HHW + (r0 + ty * 16) * 128 + tx;
#pragma unroll
    for (int i = 0; i < 16; i++) {
        lp += 130;
        float b0 = lp[0], b1 = lp[1], b2 = lp[2];
        float a0 = t0 * w00 + t1 * w01 + t2 * w02;
        float a1 = m0 * w10 + m1 * w11 + m2 * w12;
        float a2 = b0 * w20 + b1 * w21 + b2 * w22;
        yp[i * 128] = a0 + a1 + a2;
        t0 = m0; t1 = m1; t2 = m2;
        m0 = b0; m1 = b1; m2 = b2;
    }
}

// ---------------------------------------------------------------------------
// K5a: L2 norms over spatial dim for q (ch 0..127) and k (ch 128..255)
__global__ void k_norms(const float* __restrict__ qkv, float* __restrict__ norms) {
    int blk = blockIdx.x;          // B*256
    int b = blk >> 8;
    int ch = blk & 255;
    const float* p = qkv + ((size_t)b * 384 + ch) * HHW;
    float s = 0.f;
    for (int i = threadIdx.x; i < HHW; i += 256) {
        float v = p[i];
        s = fmaf(v, v, s);
    }
#pragma unroll
    for (int off = 32; off > 0; off >>= 1) s += __shfl_down(s, off);
    __shared__ float red[4];
    int lane = threadIdx.x & 63, wid = threadIdx.x >> 6;
    if (lane == 0) red[wid] = s;
    __syncthreads();
    if (threadIdx.x == 0) {
        float t = red[0] + red[1] + red[2] + red[3];
        norms[b * 256 + ch] = fmaxf(sqrtf(t), 1e-12f);
    }
}

// ---------------------------------------------------------------------------
// K5b: partial S over N-chunks. grid (B*8*16, NCHUNK).
__global__ void k_attn_s(const float* __restrict__ qkv, float* __restrict__ Spart) {
    int blk = blockIdx.x;
    int chunk = blockIdx.y;
    int ci = blk & 15;
    int hd = (blk >> 4) & 7;
    int b  = blk >> 7;
    const float* q = qkv + ((size_t)b * 384 + hd * CHEAD + ci) * HHW;
    const float* k = qkv + ((size_t)b * 384 + 128 + hd * CHEAD) * HHW;

    float acc[16];
#pragma unroll
    for (int cj = 0; cj < 16; cj++) acc[cj] = 0.f;

    int n0 = chunk * (HHW / NCHUNK);
    int n1 = n0 + (HHW / NCHUNK);
    for (int n = n0 + threadIdx.x; n < n1; n += 256) {
        float qv = q[n];
#pragma unroll
        for (int cj = 0; cj < 16; cj++) acc[cj] = fmaf(qv, k[(size_t)cj * HHW + n], acc[cj]);
    }

    __shared__ float red[4][16];
    int lane = threadIdx.x & 63, wid = threadIdx.x >> 6;
#pragma unroll
    for (int cj = 0; cj < 16; cj++) {
        float v = acc[cj];
#pragma unroll
        for (int off = 32; off > 0; off >>= 1) v += __shfl_down(v, off);
        if (lane == 0) red[wid][cj] = v;
    }
    __syncthreads();
    if (threadIdx.x < 16) {
        int cj = threadIdx.x;
        float s = red[0][cj] + red[1][cj] + red[2][cj] + red[3][cj];
        Spart[(size_t)chunk * 4096 + ((((size_t)b * 8 + hd) * 16 + ci) * 16 + cj)] = s;
    }
}

// K5c: attn = relu( (sum_chunks Spart)/(qn*kn) * temp[h] )
__global__ void k_attn_norm(const float* __restrict__ Spart, const float* __restrict__ norms,
                            const float* __restrict__ temp, float* __restrict__ attn) {
    int i = blockIdx.x * 256 + threadIdx.x;  // 4096
    if (i >= BB * 8 * 16 * 16) return;
    int cj = i & 15, ci = (i >> 4) & 15, hd = (i >> 8) & 7, b = i >> 11;
    float s = 0.f;
#pragma unroll
    for (int ch = 0; ch < NCHUNK; ch++) s += Spart[(size_t)ch * 4096 + i];
    float qn = norms[b * 256 + hd * CHEAD + ci];
    float kn = norms[b * 256 + 128 + hd * CHEAD + cj];
    attn[i] = fmaxf(s / (qn * kn) * temp[hd], 0.f);
}

// ---------------------------------------------------------------------------
// K6: one head per block: out[b,hd*16+ci,n] = sum_cj attn[ci,cj]*v[cj,n]
__global__ void k_attn_apply(const float* __restrict__ qkv, const float* __restrict__ attn,
                             float* __restrict__ out) {
    int n = blockIdx.x * 256 + threadIdx.x;
    int hd = blockIdx.y;
    int b = blockIdx.z;

    __shared__ float at[256];
    at[threadIdx.x] = attn[((size_t)b * 8 + hd) * 256 + threadIdx.x];
    __syncthreads();

    const float* v = qkv + ((size_t)b * 384 + 256 + hd * CHEAD) * HHW + n;
    float vv[16];
#pragma unroll
    for (int cj = 0; cj < 16; cj++) vv[cj] = v[(size_t)cj * HHW];

    float* ob = out + ((size_t)b * 128 + hd * CHEAD) * HHW + n;
#pragma unroll
    for (int ci = 0; ci < 16; ci++) {
        float acc = 0.f;
        const float* ar = &at[ci * 16];
#pragma unroll
        for (int cj = 0; cj < 16; cj++) acc = fmaf(ar[cj], vv[cj], acc);
        ob[(size_t)ci * HHW] = acc;
    }
}

// ---------------------------------------------------------------------------
// K8: fused wgen + dynamic 7x7 grouped conv — tap-outer, spill-free.
__global__ void k_dyn(const float* __restrict__ oa, const float* __restrict__ t,
                      const float* __restrict__ w2, const float* __restrict__ b2,
                      float* __restrict__ od) {
    int tile = blockIdx.x;
    int g = blockIdx.y;
    int b = blockIdx.z;
    int ty0 = (tile >> 3) * 16, tx0 = (tile & 7) * 16;
    int ty = threadIdx.x >> 4, tx = threadIdx.x & 15;
    int y = ty0 + ty, x = tx0 + tx;

    // stage out_attn patch: 8 ch x 22 x 22
    __shared__ __align__(16) float patch[8][22][22];
    const float* oab = oa + ((size_t)b * 128 + g * GC) * HHW;
    for (int i = threadIdx.x; i < 8 * 22 * 22; i += 256) {
        int cc = i / 484;
        int rem = i % 484;
        int py = rem / 22, px = rem % 22;
        int sy = ty0 + py - 3, sx = tx0 + px - 3;
        float v = 0.f;
        if (sy >= 0 && sy < 128 && sx >= 0 && sx < 128)
            v = oab[(size_t)cc * HHW + sy * 128 + sx];
        patch[cc][py][px] = v;
    }
    __syncthreads();

    // t[32] for this pixel -> registers (coalesced loads)
    const float* tb = t + (size_t)b * 32 * HHW + y * 128 + x;
    float tv[32];
#pragma unroll
    for (int m = 0; m < 32; m++) tv[m] = tb[(size_t)m * HHW];

    const float* w2g = w2 + (size_t)g * 49 * 32;
    const float* b2g = b2 + (size_t)g * 49;

    float acc[8];
#pragma unroll
    for (int cc = 0; cc < 8; cc++) acc[cc] = 0.f;

    for (int kk = 0; kk < 49; kk++) {
        float w0 = b2g[kk], w1 = 0.f;
        const float* wr = &w2g[kk * 32];
#pragma unroll
        for (int m = 0; m < 32; m += 2) {
            w0 = fmaf(wr[m],     tv[m],     w0);
            w1 = fmaf(wr[m + 1], tv[m + 1], w1);
        }
        float wv = w0 + w1;
        int di = kk / 7, dj = kk % 7;
#pragma unroll
        for (int cc = 0; cc < 8; cc++)
            acc[cc] = fmaf(patch[cc][ty + di][tx + dj], wv, acc[cc]);
    }

    float* odb = od + ((size_t)b * 128 + g * GC) * HHW + y * 128 + x;
#pragma unroll
    for (int cc = 0; cc < 8; cc++) odb[(size_t)cc * HHW] = acc[cc];
}

// ---------------------------------------------------------------------------
// K9: fused inverse DWT + projection
__global__ void k_idwt_proj(const float* __restrict__ dyn, const float* __restrict__ pw,
                            float* __restrict__ out) {
    int p = blockIdx.x * 256 + threadIdx.x;   // half-res pixel
    int oc0 = blockIdx.y * 16;
    int b = blockIdx.z;
    int y = p >> 7, x = p & 127;

    __shared__ __align__(16) float wl[32 * 16];   // wl[c*16+oc]
    for (int i = threadIdx.x; i < 512; i += 256) {
        int oc = i & 15, c = i >> 4;
        wl[i] = pw[(size_t)(oc0 + oc) * 32 + c];
    }
    __syncthreads();

    float u0[16], u1[16], u2[16], u3[16];
#pragma unroll
    for (int oc = 0; oc < 16; oc++) { u0[oc]=0.f; u1[oc]=0.f; u2[oc]=0.f; u3[oc]=0.f; }

    const float* db = dyn + (size_t)b * 128 * HHW + p;
    for (int c = 0; c < 32; c++) {
        float d0 = db[(size_t)(0 * 32 + c) * HHW];
        float d1 = db[(size_t)(1 * 32 + c) * HHW];
        float d2 = db[(size_t)(2 * 32 + c) * HHW];
        float d3 = db[(size_t)(3 * 32 + c) * HHW];
        const float* wc = &wl[c * 16];
#pragma unroll
        for (int oc = 0; oc < 16; oc++) {
            float wv = wc[oc];
            u0[oc] = fmaf(wv, d0, u0[oc]);
            u1[oc] = fmaf(wv, d1, u1[oc]);
            u2[oc] = fmaf(wv, d2, u2[oc]);
            u3[oc] = fmaf(wv, d3, u3[oc]);
        }
    }

    float* ob = out + ((size_t)b * 128 + oc0) * HWFULL + (2 * y) * 256 + 2 * x;
#pragma unroll
    for (int oc = 0; oc < 16; oc++) {
        float a = u0[oc], bq = u1[oc], c2 = u2[oc], dd = u3[oc];
        float2 top, bot;
        top.x = 0.5f * (a + bq + c2 + dd);
        top.y = 0.5f * (a + bq - c2 - dd);
        bot.x = 0.5f * (a - bq + c2 - dd);
        bot.y = 0.5f * (a - bq - c2 + dd);
        float* o = ob + (size_t)oc * HWFULL;
        *reinterpret_cast<float2*>(&o[0])   = top;
        *reinterpret_cast<float2*>(&o[256]) = bot;
    }
}

// ---------------------------------------------------------------------------
extern "C" void kernel_launch(void* const* d_in, const int* in_sizes, int n_in,
                              void* d_out, int out_size, void* d_ws, size_t ws_size,
                              hipStream_t stream) {
    const float* x        = (const float*)d_in[0];
    const float* reduce_w = (const float*)d_in[1];
    const float* reduce_b = (const float*)d_in[2];
    const float* qkv_w    = (const float*)d_in[3];
    const float* qkv_dw   = (const float*)d_in[4];
    const float* temp     = (const float*)d_in[5];
    const float* fil_w1   = (const float*)d_in[6];
    const float* fil_b1   = (const float*)d_in[7];
    const float* fil_w2   = (const float*)d_in[8];
    const float* fil_b2   = (const float*)d_in[9];
    const float* proj_w   = (const float*)d_in[10];
    float* out = (float*)d_out;

    // workspace layout (floats)
    float* ws = (float*)d_ws;
    float* x_dwt = ws;                                   // B*128*16384
    float* big   = x_dwt + (size_t)BB * 128 * HHW;       // B*384*16384: qkv0 -> out_attn
    float* qkv1  = big   + (size_t)BB * 384 * HHW;       // B*384*16384
    float* tbuf  = qkv1  + (size_t)BB * 384 * HHW;       // B*32*16384
    float* norms = tbuf  + (size_t)BB * 32 * HHW;        // 512
    float* Spart = norms + 512;                          // NCHUNK*4096
    float* attn  = Spart + NCHUNK * 4096;                // 4096
    float* qkv0 = big;
    float* out_attn = big;     // alias (qkv0 dead after dw3x3)
    float* out_dyn = x_dwt;    // alias (x_dwt dead after t computed)

    // 1+2. fused reduce conv + relu + Haar DWT (round-5 validated version)
    k_reduce_dwt<<<dim3(HHW / 128, 4, BB), 128, 0, stream>>>(x, reduce_w, reduce_b, x_dwt);
    // 3. qkv pointwise (float4 pixels, scalar weights)
    k_conv1x1_f4<16, 128><<<dim3(HHW / 1024, 384 / 16, BB), 256, 0, stream>>>(
        x_dwt, qkv_w, qkv0, 384, HHW);
    // 4. depthwise 3x3 (LDS-tiled)
    k_dw3x3<<<dim3(BB * 384 * 4), 256, 0, stream>>>(qkv0, qkv_dw, qkv1);
    // 5. attention
    k_norms<<<dim3(BB * 256), 256, 0, stream>>>(qkv1, norms);
    k_attn_s<<<dim3(BB * 8 * 16, NCHUNK), 256, 0, stream>>>(qkv1, Spart);
    k_attn_norm<<<dim3(16), 256, 0, stream>>>(Spart, norms, temp, attn);
    k_attn_apply<<<dim3(HHW / 256, HEADS, BB), 256, 0, stream>>>(qkv1, attn, out_attn);
    // 6. filter branch: t = relu(W1 @ x_dwt + b1)  (scalar weights)
    k_conv1x1<1, 8, 128><<<dim3(HHW / 256, 4, BB), 256, 0, stream>>>(
        x_dwt, fil_w1, fil_b1, tbuf, 32, HHW, 1);
    // 7. fused wgen + dynamic conv (tap-outer)
    k_dyn<<<dim3(64, GG, BB), 256, 0, stream>>>(out_attn, tbuf, fil_w2, fil_b2, out_dyn);
    // 8. fused idwt + projection
    k_idwt_proj<<<dim3(HHW / 256, 8, BB), 256, 0, stream>>>(out_dyn, proj_w, out);
}